// Round 4
// baseline (156.760 us; speedup 1.0000x reference)
//
#include <hip/hip_runtime.h>

// mixture/target/noise: (N, 2, C, T, F) float32
#define Nn 4
#define Cc 8
#define Tt 256
#define Ff 513
#define TFs (Tt * Ff)      // 131328
#define NCHUNK 16
#define TCHUNK (Tt / NCHUNK)        // 16 t-steps per chunk
#define SLAB ((size_t)Ff * 72)      // floats per (inp,n,chunk) slab

// ---------------------------------------------------------------------------
// Stage 1: partial covariances. 256-thread block = 4 waves; wave G computes
// Hermitian rows {G, 7-G} (9 pairs, 16 accumulators) over ALL TCHUNK t-steps.
// The pair-split's redundant channel reads are intra-block: the lighter waves
// run ahead and prefetch; L1/L2 serves the overlap so HBM fetch stays ~1x.
// Waves own disjoint pair sets -> NO cross-wave reduction; single LDS region
// [64][73] (18.7 KB) -> 8 blocks/CU = 32 waves/CU (full occupancy), then one
// barrier + cooperative coalesced store of the [64 f][72] slab.
// Partial layout [inp][n][chunk][f][72]: 72 components of one f contiguous.
// ---------------------------------------------------------------------------
template <int G>
__device__ __forceinline__ void cov_group(const float* __restrict__ bt,
                                          float (*red)[73], int lane)
{
    constexpr int R2 = 7 - G;
    float ar[9], ai[9];
#pragma unroll
    for (int s = 0; s < 9; ++s) { ar[s] = 0.f; ai[s] = 0.f; }

#pragma unroll 2
    for (int tt = 0; tt < TCHUNK; ++tt) {
        float re[8], im[8];
#pragma unroll
        for (int c = G; c < 8; ++c) {
            re[c] = bt[(size_t)c * TFs];
            im[c] = bt[(size_t)(Cc + c) * TFs];
        }
        int s = 0;
#pragma unroll
        for (int d = G; d < 8; ++d, ++s) {          // row G
            ar[s] += re[G] * re[d] + im[G] * im[d];
            if (d != G) ai[s] += im[G] * re[d] - re[G] * im[d];
        }
#pragma unroll
        for (int d = R2; d < 8; ++d, ++s) {         // row 7-G
            ar[s] += re[R2] * re[d] + im[R2] * im[d];
            if (d != R2) ai[s] += im[R2] * re[d] - re[R2] * im[d];
        }
        bt += Ff;
    }

    int s = 0;
#pragma unroll
    for (int d = G; d < 8; ++d, ++s) {
        const int p = G * 8 - G * (G - 1) / 2 + (d - G);
        red[lane][2 * p]     = ar[s];
        red[lane][2 * p + 1] = (d == G) ? 0.f : ai[s];
    }
#pragma unroll
    for (int d = R2; d < 8; ++d, ++s) {
        const int p = R2 * 8 - R2 * (R2 - 1) / 2 + (d - R2);
        red[lane][2 * p]     = ar[s];
        red[lane][2 * p + 1] = (d == R2) ? 0.f : ai[s];
    }
}

__global__ __launch_bounds__(256) void cov_partial(
    const float* __restrict__ target, const float* __restrict__ noise,
    float* __restrict__ partial)
{
    int tid = threadIdx.x;
    int lane = tid & 63, wave = tid >> 6;
    int f0 = blockIdx.x * 64;
    int f = f0 + lane;
    int fc = f < Ff ? f : (Ff - 1);        // clamp: no early return (barrier!)
    int n = blockIdx.y;
    int z = blockIdx.z;                    // z = chunk*2 + inp
    int inp = z & 1;
    int chunk = z >> 1;

    const float* src = inp ? noise : target;
    const float* bt = src + (size_t)n * 2 * Cc * TFs
                      + (size_t)(chunk * TCHUNK) * Ff + fc;

    __shared__ float red[64][73];          // stride 73: (9*lane+j)%32 conflict-free
    switch (wave) {
        case 0: cov_group<0>(bt, red, lane); break;
        case 1: cov_group<1>(bt, red, lane); break;
        case 2: cov_group<2>(bt, red, lane); break;
        default: cov_group<3>(bt, red, lane); break;
    }
    __syncthreads();

    // cooperative coalesced store of the [64 f][72] slab
    int nf = Ff - f0; if (nf > 64) nf = 64;
    float* dst = partial + (((size_t)inp * Nn + n) * NCHUNK + chunk) * SLAB
                 + (size_t)f0 * 72;
    for (int i = tid; i < nf * 72; i += 256) {
        int fl = i / 72, j = i - fl * 72;
        dst[i] = red[fl][j];
    }
}

// ---------------------------------------------------------------------------
// Stage 2: chunk-reduce + wave-parallel MVDR solve. ONE wave per (n,f).
// Lane (r,c) = entry (r,c); lane float2-loads its pair from each 288 B slab
// window (coalesced), fully-unrolled independent loads. Gauss-Jordan with
// partial pivoting on [phiN | phiT] -> B = G = phiN^{-1} phiT; all cross-lane
// traffic via shuffles, zero barriers.
// ---------------------------------------------------------------------------
__global__ __launch_bounds__(64) void mvdr_weights(
    const float* __restrict__ partial, const int* __restrict__ ref_ptr,
    float2* __restrict__ wconj)
{
    int f = blockIdx.x;
    int n = blockIdx.y;
    int lane = threadIdx.x;

    int r = lane >> 3, c = lane & 7;
    int lo = r < c ? r : c, hi = r < c ? c : r;
    int p = lo * 8 - lo * (lo - 1) / 2 + (hi - lo);

    const float* pT = partial + ((size_t)(0 * Nn + n) * NCHUNK) * SLAB
                      + (size_t)f * 72 + 2 * p;
    const float* pN = partial + ((size_t)(1 * Nn + n) * NCHUNK) * SLAB
                      + (size_t)f * 72 + 2 * p;
    float2 sT = make_float2(0.f, 0.f), sN = make_float2(0.f, 0.f);
#pragma unroll
    for (int ch = 0; ch < NCHUNK; ++ch) {
        float2 vT = *(const float2*)(pT + ch * SLAB);
        float2 vN = *(const float2*)(pN + ch * SLAB);
        sT.x += vT.x; sT.y += vT.y;
        sN.x += vN.x; sN.y += vN.y;
    }

    const float invT = 1.0f / (float)Tt;
    const float dl = 0.001f / 1.41421356237309515f;   // 0.001/sqrt(2)
    float sgn = (r > c) ? -1.f : 1.f;                 // Hermitian reconstruction

    float2 a = make_float2(sN.x * invT, sgn * sN.y * invT);
    float2 b = make_float2(sT.x * invT, sgn * sT.y * invT);
    if (r == c) { a.x += dl; a.y += dl; }             // complex diagonal loading

    for (int k = 0; k < 8; ++k) {
        // --- argmax |A_{jk}|^2 over j >= k (butterfly) ---
        float mag = (c == k && r >= k) ? (a.x * a.x + a.y * a.y) : -1.f;
        int midx = r;
#pragma unroll
        for (int st = 8; st < 64; st <<= 1) {
            float om = __shfl_xor(mag, st, 64);
            int   oi = __shfl_xor(midx, st, 64);
            if (om > mag) { mag = om; midx = oi; }
        }
        int piv = __shfl(midx, k, 64);

        // --- swap rows k <-> piv ---
        int srcr = (r == k) ? piv : ((r == piv) ? k : r);
        int src = srcr * 8 + c;
        a.x = __shfl(a.x, src, 64); a.y = __shfl(a.y, src, 64);
        b.x = __shfl(b.x, src, 64); b.y = __shfl(b.y, src, 64);

        // --- scale row k by 1/pivot ---
        float pvx = __shfl(a.x, k * 8 + k, 64), pvy = __shfl(a.y, k * 8 + k, 64);
        float d = pvx * pvx + pvy * pvy;
        float ipx = pvx / d, ipy = -pvy / d;
        if (r == k) {
            float2 t = a;
            a = make_float2(t.x * ipx - t.y * ipy, t.x * ipy + t.y * ipx);
            t = b;
            b = make_float2(t.x * ipx - t.y * ipy, t.x * ipy + t.y * ipx);
        }

        // --- eliminate all other rows ---
        float rax = __shfl(a.x, k * 8 + c, 64), ray = __shfl(a.y, k * 8 + c, 64);
        float rbx = __shfl(b.x, k * 8 + c, 64), rby = __shfl(b.y, k * 8 + c, 64);
        float fx  = __shfl(a.x, r * 8 + k, 64), fy  = __shfl(a.y, r * 8 + k, 64);
        if (r != k) {
            a.x -= fx * rax - fy * ray;  a.y -= fx * ray + fy * rax;
            b.x -= fx * rbx - fy * rby;  b.y -= fx * rby + fy * rbx;
        }
    }

    // --- l = trace(G): full-wave sum of diagonal entries of B ---
    float tx = (r == c) ? b.x : 0.f, ty = (r == c) ? b.y : 0.f;
#pragma unroll
    for (int st = 1; st < 64; st <<= 1) {
        tx += __shfl_xor(tx, st, 64);
        ty += __shfl_xor(ty, st, 64);
    }

    int ref = *ref_ptr;
    if (c == ref) {                                   // lane (r, ref) holds G_{r,ref}
        float den = tx * tx + ty * ty;
        float wx = (b.x * tx + b.y * ty) / den;       // W = G[:,ref] / l
        float wy = (b.y * tx - b.x * ty) / den;
        wconj[((size_t)n * Ff + f) * 8 + r] = make_float2(wx, -wy);  // conj(W)
    }
}

// ---------------------------------------------------------------------------
// Stage 3: X_bf(n,t,f) = sum_c conj(W)(n,f,c) * y(n,c,t,f)
// ---------------------------------------------------------------------------
__global__ __launch_bounds__(256) void beamform(
    const float* __restrict__ y, const float2* __restrict__ wconj,
    float* __restrict__ out)
{
    int idx = blockIdx.x * 256 + threadIdx.x;   // < N*T*F = 525312
    int n = idx / TFs;
    int rem = idx - n * TFs;
    int t = rem / Ff;
    int f = rem - t * Ff;

    size_t base_re = (size_t)n * 2 * Cc * TFs + (size_t)t * Ff + f;
    size_t base_im = base_re + (size_t)Cc * TFs;
    const float2* w = wconj + ((size_t)n * Ff + f) * 8;

    float xr = 0.f, xi = 0.f;
#pragma unroll
    for (int c = 0; c < Cc; ++c) {
        float yre = y[base_re + (size_t)c * TFs];
        float yim = y[base_im + (size_t)c * TFs];
        float2 wc = w[c];
        xr += wc.x * yre - wc.y * yim;
        xi += wc.x * yim + wc.y * yre;
    }
    size_t ob = (size_t)n * 2 * TFs + (size_t)t * Ff + f;
    out[ob] = xr;
    out[ob + TFs] = xi;
}

extern "C" void kernel_launch(void* const* d_in, const int* in_sizes, int n_in,
                              void* d_out, int out_size, void* d_ws, size_t ws_size,
                              hipStream_t stream) {
    const float* mixture = (const float*)d_in[0];
    const float* target  = (const float*)d_in[1];
    const float* noise   = (const float*)d_in[2];
    const int*   refp    = (const int*)d_in[3];
    float* out = (float*)d_out;

    // partial: 2 * Nn * NCHUNK * Ff * 72 floats = ~18.9 MB (ws is ~256 MB)
    float*  partial = (float*)d_ws;
    float2* wconj = (float2*)((char*)d_ws +
                              (size_t)2 * Nn * NCHUNK * SLAB * sizeof(float));

    cov_partial<<<dim3(9, Nn, NCHUNK * 2), 256, 0, stream>>>(target, noise, partial);
    mvdr_weights<<<dim3(Ff, Nn), 64, 0, stream>>>(partial, refp, wconj);
    beamform<<<dim3((Nn * TFs) / 256), 256, 0, stream>>>(mixture, wconj, out);
}

// Round 5
// 150.782 us; speedup vs baseline: 1.0396x; 1.0396x over previous
//
#include <hip/hip_runtime.h>

// mixture/target/noise: (N, 2, C, T, F) float32
#define Nn 4
#define Cc 8
#define Tt 256
#define Ff 513
#define TFs (Tt * Ff)      // 131328
#define NCHUNK 16
#define TCHUNK (Tt / NCHUNK)        // 16 t-steps per chunk
#define SLAB ((size_t)Ff * 72)      // floats per (inp,n,chunk) slab

// ---------------------------------------------------------------------------
// Stage 1: partial covariances, LDS-staged.
// Block = 256 thr = 4 waves. Per t-PAIR the block cooperatively stages all 16
// channel rows (re0-7,im0-7; 64 f each) into a double-buffered LDS region:
// every HBM element is read EXACTLY once (fixes round-4's 1.67x overfetch).
// Wave G owns Hermitian rows {G, 7-G} (9 pairs, 18 accumulators) -> ~55 VGPR
// -> 8 waves/SIMD (round-2/3 full-pair waves were VGPR-quantized to 4/SIMD).
// Register prefetch of pair t+2 during compute of pair t keeps ~8 KB of HBM
// in flight per block. Pair sets are disjoint -> no cross-wave reduction; the
// staging buffer is re-aliased as the [64][73] store-staging region (union
// keeps LDS at 18.7 KB -> 8 blocks/CU possible).
// Partial layout [inp][n][chunk][f][72]: 72 components of one f contiguous.
// ---------------------------------------------------------------------------

// rows layout: flat offset ((buf*16 + chan)*2 + j)*64 + lane   (buf,j in 0..1)
#define ROWS(Rbase, chan, j) ((Rbase) + (((chan) * 2 + (j)) * 64))

template <int G>
__device__ __forceinline__ void cov_wave(const float* __restrict__ base,
                                         float* __restrict__ smem, int lane)
{
    constexpr int R2 = 7 - G;
    float* buf0 = smem;                 // 2048 floats
    float* buf1 = smem + 2048;

    float ar[9], ai[9];
#pragma unroll
    for (int s = 0; s < 9; ++s) { ar[s] = 0.f; ai[s] = 0.f; }

    // this wave stages channels 4G..4G+3 (0..7 = re, 8..15 = im)
    const float* g0 = base + (size_t)(4 * G + 0) * TFs;
    const float* g1 = base + (size_t)(4 * G + 1) * TFs;
    const float* g2 = base + (size_t)(4 * G + 2) * TFs;
    const float* g3 = base + (size_t)(4 * G + 3) * TFs;

    // consume one t-pair from buffer R
#define ACCUM_PAIR(R)                                                         \
    do {                                                                      \
        _Pragma("unroll")                                                     \
        for (int j = 0; j < 2; ++j) {                                         \
            float re[8], im[8];                                               \
            _Pragma("unroll")                                                 \
            for (int c2 = G; c2 < 8; ++c2) {                                  \
                re[c2] = ROWS(R, c2, j)[lane];                                \
                im[c2] = ROWS(R, 8 + c2, j)[lane];                            \
            }                                                                 \
            int s = 0;                                                        \
            _Pragma("unroll")                                                 \
            for (int d = G; d < 8; ++d, ++s) {                                \
                ar[s] += re[G] * re[d] + im[G] * im[d];                       \
                if (d != G) ai[s] += im[G] * re[d] - re[G] * im[d];           \
            }                                                                 \
            _Pragma("unroll")                                                 \
            for (int d = R2; d < 8; ++d, ++s) {                               \
                ar[s] += re[R2] * re[d] + im[R2] * im[d];                     \
                if (d != R2) ai[s] += im[R2] * re[d] - re[R2] * im[d];        \
            }                                                                 \
        }                                                                     \
    } while (0)

    // prologue: load t-pair 0 (t=0,1) -> buf0
    {
        float a0 = g0[0], b0 = g0[Ff], a1 = g1[0], b1 = g1[Ff];
        float a2 = g2[0], b2 = g2[Ff], a3 = g3[0], b3 = g3[Ff];
        g0 += 2 * Ff; g1 += 2 * Ff; g2 += 2 * Ff; g3 += 2 * Ff;
        ROWS(buf0, 4 * G + 0, 0)[lane] = a0; ROWS(buf0, 4 * G + 0, 1)[lane] = b0;
        ROWS(buf0, 4 * G + 1, 0)[lane] = a1; ROWS(buf0, 4 * G + 1, 1)[lane] = b1;
        ROWS(buf0, 4 * G + 2, 0)[lane] = a2; ROWS(buf0, 4 * G + 2, 1)[lane] = b2;
        ROWS(buf0, 4 * G + 3, 0)[lane] = a3; ROWS(buf0, 4 * G + 3, 1)[lane] = b3;
    }

    // 8 pair-phases, 2 per loop iteration (static buffer indices)
    for (int ph = 0; ph < 8; ph += 2) {
        __syncthreads();                       // buf0 (pair ph) visible
        {   // prefetch pair ph+1 early, consume buf0, write buf1
            float a0 = g0[0], b0 = g0[Ff], a1 = g1[0], b1 = g1[Ff];
            float a2 = g2[0], b2 = g2[Ff], a3 = g3[0], b3 = g3[Ff];
            g0 += 2 * Ff; g1 += 2 * Ff; g2 += 2 * Ff; g3 += 2 * Ff;
            ACCUM_PAIR(buf0);
            ROWS(buf1, 4 * G + 0, 0)[lane] = a0; ROWS(buf1, 4 * G + 0, 1)[lane] = b0;
            ROWS(buf1, 4 * G + 1, 0)[lane] = a1; ROWS(buf1, 4 * G + 1, 1)[lane] = b1;
            ROWS(buf1, 4 * G + 2, 0)[lane] = a2; ROWS(buf1, 4 * G + 2, 1)[lane] = b2;
            ROWS(buf1, 4 * G + 3, 0)[lane] = a3; ROWS(buf1, 4 * G + 3, 1)[lane] = b3;
        }
        __syncthreads();                       // buf1 (pair ph+1) visible
        if (ph < 6) {                          // prefetch pair ph+2, write buf0
            float a0 = g0[0], b0 = g0[Ff], a1 = g1[0], b1 = g1[Ff];
            float a2 = g2[0], b2 = g2[Ff], a3 = g3[0], b3 = g3[Ff];
            g0 += 2 * Ff; g1 += 2 * Ff; g2 += 2 * Ff; g3 += 2 * Ff;
            ACCUM_PAIR(buf1);
            ROWS(buf0, 4 * G + 0, 0)[lane] = a0; ROWS(buf0, 4 * G + 0, 1)[lane] = b0;
            ROWS(buf0, 4 * G + 1, 0)[lane] = a1; ROWS(buf0, 4 * G + 1, 1)[lane] = b1;
            ROWS(buf0, 4 * G + 2, 0)[lane] = a2; ROWS(buf0, 4 * G + 2, 1)[lane] = b2;
            ROWS(buf0, 4 * G + 3, 0)[lane] = a3; ROWS(buf0, 4 * G + 3, 1)[lane] = b3;
        } else {
            ACCUM_PAIR(buf1);
        }
    }
#undef ACCUM_PAIR

    __syncthreads();   // all rows consumed -> safe to alias smem as red[64][73]
    float (*red)[73] = (float(*)[73])smem;     // stride 73: conflict-free
    int s = 0;
#pragma unroll
    for (int d = G; d < 8; ++d, ++s) {
        const int p = G * 8 - G * (G - 1) / 2 + (d - G);
        red[lane][2 * p]     = ar[s];
        red[lane][2 * p + 1] = (d == G) ? 0.f : ai[s];
    }
#pragma unroll
    for (int d = R2; d < 8; ++d, ++s) {
        const int p = R2 * 8 - R2 * (R2 - 1) / 2 + (d - R2);
        red[lane][2 * p]     = ar[s];
        red[lane][2 * p + 1] = (d == R2) ? 0.f : ai[s];
    }
}

__global__ __launch_bounds__(256, 8) void cov_partial(
    const float* __restrict__ target, const float* __restrict__ noise,
    float* __restrict__ partial)
{
    int tid = threadIdx.x;
    int lane = tid & 63, wave = tid >> 6;
    int f0 = blockIdx.x * 64;
    int f = f0 + lane;
    int fc = f < Ff ? f : (Ff - 1);        // clamp: no early return (barriers!)
    int n = blockIdx.y;
    int z = blockIdx.z;                    // z = chunk*2 + inp
    int inp = z & 1;
    int chunk = z >> 1;

    const float* src = inp ? noise : target;
    const float* base = src + (size_t)n * 2 * Cc * TFs
                        + (size_t)(chunk * TCHUNK) * Ff + fc;

    __shared__ float smem[64 * 73];        // 18688 B: rows dbuf (16 KB) / red
    switch (wave) {
        case 0: cov_wave<0>(base, smem, lane); break;
        case 1: cov_wave<1>(base, smem, lane); break;
        case 2: cov_wave<2>(base, smem, lane); break;
        default: cov_wave<3>(base, smem, lane); break;
    }
    __syncthreads();

    // cooperative coalesced store of the [64 f][72] slab
    int nf = Ff - f0; if (nf > 64) nf = 64;
    float (*red)[73] = (float(*)[73])smem;
    float* dst = partial + (((size_t)inp * Nn + n) * NCHUNK + chunk) * SLAB
                 + (size_t)f0 * 72;
    for (int i = tid; i < nf * 72; i += 256) {
        int fl = i / 72, j = i - fl * 72;
        dst[i] = red[fl][j];
    }
}

// ---------------------------------------------------------------------------
// Stage 2: chunk-reduce + wave-parallel MVDR solve. ONE wave per (n,f).
// Lane (r,c) = entry (r,c); lane float2-loads its pair from each 288 B slab
// window (coalesced), fully-unrolled independent loads. Gauss-Jordan with
// partial pivoting on [phiN | phiT] -> B = G = phiN^{-1} phiT; all cross-lane
// traffic via shuffles, zero barriers.
// ---------------------------------------------------------------------------
__global__ __launch_bounds__(64) void mvdr_weights(
    const float* __restrict__ partial, const int* __restrict__ ref_ptr,
    float2* __restrict__ wconj)
{
    int f = blockIdx.x;
    int n = blockIdx.y;
    int lane = threadIdx.x;

    int r = lane >> 3, c = lane & 7;
    int lo = r < c ? r : c, hi = r < c ? c : r;
    int p = lo * 8 - lo * (lo - 1) / 2 + (hi - lo);

    const float* pT = partial + ((size_t)(0 * Nn + n) * NCHUNK) * SLAB
                      + (size_t)f * 72 + 2 * p;
    const float* pN = partial + ((size_t)(1 * Nn + n) * NCHUNK) * SLAB
                      + (size_t)f * 72 + 2 * p;
    float2 sT = make_float2(0.f, 0.f), sN = make_float2(0.f, 0.f);
#pragma unroll
    for (int ch = 0; ch < NCHUNK; ++ch) {
        float2 vT = *(const float2*)(pT + ch * SLAB);
        float2 vN = *(const float2*)(pN + ch * SLAB);
        sT.x += vT.x; sT.y += vT.y;
        sN.x += vN.x; sN.y += vN.y;
    }

    const float invT = 1.0f / (float)Tt;
    const float dl = 0.001f / 1.41421356237309515f;   // 0.001/sqrt(2)
    float sgn = (r > c) ? -1.f : 1.f;                 // Hermitian reconstruction

    float2 a = make_float2(sN.x * invT, sgn * sN.y * invT);
    float2 b = make_float2(sT.x * invT, sgn * sT.y * invT);
    if (r == c) { a.x += dl; a.y += dl; }             // complex diagonal loading

    for (int k = 0; k < 8; ++k) {
        // --- argmax |A_{jk}|^2 over j >= k (butterfly) ---
        float mag = (c == k && r >= k) ? (a.x * a.x + a.y * a.y) : -1.f;
        int midx = r;
#pragma unroll
        for (int st = 8; st < 64; st <<= 1) {
            float om = __shfl_xor(mag, st, 64);
            int   oi = __shfl_xor(midx, st, 64);
            if (om > mag) { mag = om; midx = oi; }
        }
        int piv = __shfl(midx, k, 64);

        // --- swap rows k <-> piv ---
        int srcr = (r == k) ? piv : ((r == piv) ? k : r);
        int src = srcr * 8 + c;
        a.x = __shfl(a.x, src, 64); a.y = __shfl(a.y, src, 64);
        b.x = __shfl(b.x, src, 64); b.y = __shfl(b.y, src, 64);

        // --- scale row k by 1/pivot ---
        float pvx = __shfl(a.x, k * 8 + k, 64), pvy = __shfl(a.y, k * 8 + k, 64);
        float d = pvx * pvx + pvy * pvy;
        float ipx = pvx / d, ipy = -pvy / d;
        if (r == k) {
            float2 t = a;
            a = make_float2(t.x * ipx - t.y * ipy, t.x * ipy + t.y * ipx);
            t = b;
            b = make_float2(t.x * ipx - t.y * ipy, t.x * ipy + t.y * ipx);
        }

        // --- eliminate all other rows ---
        float rax = __shfl(a.x, k * 8 + c, 64), ray = __shfl(a.y, k * 8 + c, 64);
        float rbx = __shfl(b.x, k * 8 + c, 64), rby = __shfl(b.y, k * 8 + c, 64);
        float fx  = __shfl(a.x, r * 8 + k, 64), fy  = __shfl(a.y, r * 8 + k, 64);
        if (r != k) {
            a.x -= fx * rax - fy * ray;  a.y -= fx * ray + fy * rax;
            b.x -= fx * rbx - fy * rby;  b.y -= fx * rby + fy * rbx;
        }
    }

    // --- l = trace(G): full-wave sum of diagonal entries of B ---
    float tx = (r == c) ? b.x : 0.f, ty = (r == c) ? b.y : 0.f;
#pragma unroll
    for (int st = 1; st < 64; st <<= 1) {
        tx += __shfl_xor(tx, st, 64);
        ty += __shfl_xor(ty, st, 64);
    }

    int ref = *ref_ptr;
    if (c == ref) {                                   // lane (r, ref) holds G_{r,ref}
        float den = tx * tx + ty * ty;
        float wx = (b.x * tx + b.y * ty) / den;       // W = G[:,ref] / l
        float wy = (b.y * tx - b.x * ty) / den;
        wconj[((size_t)n * Ff + f) * 8 + r] = make_float2(wx, -wy);  // conj(W)
    }
}

// ---------------------------------------------------------------------------
// Stage 3: X_bf(n,t,f) = sum_c conj(W)(n,f,c) * y(n,c,t,f)
// ---------------------------------------------------------------------------
__global__ __launch_bounds__(256) void beamform(
    const float* __restrict__ y, const float2* __restrict__ wconj,
    float* __restrict__ out)
{
    int idx = blockIdx.x * 256 + threadIdx.x;   // < N*T*F = 525312
    int n = idx / TFs;
    int rem = idx - n * TFs;
    int t = rem / Ff;
    int f = rem - t * Ff;

    size_t base_re = (size_t)n * 2 * Cc * TFs + (size_t)t * Ff + f;
    size_t base_im = base_re + (size_t)Cc * TFs;
    const float2* w = wconj + ((size_t)n * Ff + f) * 8;

    float xr = 0.f, xi = 0.f;
#pragma unroll
    for (int c = 0; c < Cc; ++c) {
        float yre = y[base_re + (size_t)c * TFs];
        float yim = y[base_im + (size_t)c * TFs];
        float2 wc = w[c];
        xr += wc.x * yre - wc.y * yim;
        xi += wc.x * yim + wc.y * yre;
    }
    size_t ob = (size_t)n * 2 * TFs + (size_t)t * Ff + f;
    out[ob] = xr;
    out[ob + TFs] = xi;
}

extern "C" void kernel_launch(void* const* d_in, const int* in_sizes, int n_in,
                              void* d_out, int out_size, void* d_ws, size_t ws_size,
                              hipStream_t stream) {
    const float* mixture = (const float*)d_in[0];
    const float* target  = (const float*)d_in[1];
    const float* noise   = (const float*)d_in[2];
    const int*   refp    = (const int*)d_in[3];
    float* out = (float*)d_out;

    // partial: 2 * Nn * NCHUNK * Ff * 72 floats = ~18.9 MB (ws is ~256 MB)
    float*  partial = (float*)d_ws;
    float2* wconj = (float2*)((char*)d_ws +
                              (size_t)2 * Nn * NCHUNK * SLAB * sizeof(float));

    cov_partial<<<dim3(9, Nn, NCHUNK * 2), 256, 0, stream>>>(target, noise, partial);
    mvdr_weights<<<dim3(Ff, Nn), 64, 0, stream>>>(partial, refp, wconj);
    beamform<<<dim3((Nn * TFs) / 256), 256, 0, stream>>>(mixture, wconj, out);
}